// Round 1
// baseline (342.351 us; speedup 1.0000x reference)
//
#include <hip/hip_runtime.h>
#include <hip/hip_bf16.h>
#include <hip/hip_cooperative_groups.h>
#include <math.h>

#define ENC 512
#define ATT 256
#define NN 1024
#define PP 1024

typedef __attribute__((ext_vector_type(8))) __bf16 bf16x8;
typedef __attribute__((ext_vector_type(4))) float floatx4;
typedef __attribute__((ext_vector_type(2))) float floatx2;

union LdsVec { uint4 u; bf16x8 v; };

// packed fp32->bf16 RNE via v_cvt_pk_bf16_f32 (gfx950)
__device__ __forceinline__ unsigned cvt_pk(float lo, float hi) {
    union { __hip_bfloat162 h; unsigned u; } x;
    x.h = __float22bfloat162_rn(float2{lo, hi});
    return x.u;
}
__device__ __forceinline__ uint4 cvt8(float4 f0, float4 f1) {
    uint4 r;
    r.x = cvt_pk(f0.x, f0.y); r.y = cvt_pk(f0.z, f0.w);
    r.z = cvt_pk(f1.x, f1.y); r.w = cvt_pk(f1.z, f1.w);
    return r;
}

// LDS tile: [rows][32 k] bf16, row stride 64B; 16B chunks XOR-swizzled.
__device__ __forceinline__ int tile_off(int row, int k) {
    return row * 32 + ((((k >> 3) ^ ((row >> 1) & 3)) & 3) << 3) + (k & 7);
}

// Shared-memory union across phases (max 16.4 KB -> 1 block/CU guaranteed).
union __align__(16) SmemU {
    struct { unsigned short As[2][2048]; unsigned short Bs[2][2048]; } g;   // P1 GEMM
    struct { unsigned short T[64][72]; } t;                                  // P1 E^T
    struct { float vsmT[256][4]; float wfs[256]; float red[2][4][4]; } att;  // P2
    struct { unsigned short As[2][1024]; unsigned short Bs[2][2048]; } aw;   // P4
};

// ---------------------------------------------------------------------------
// Phase 1 (256 blocks): z = bid>>6.
//  z=0: uT = (E@We^T+be)^T  [a=256][p=1024]  (transposed for P2 p-slicing)
//  z=1: v1 =  D@Wt^T+bt     [n=1024][a=256]  (untransposed: P2 wants rows)
//  z=2: v2 =  L@Wl^T+bl     [n=1024][a=256]
//  z=3: ET = bf16 E^T [512][1024] for phase 4.
// ---------------------------------------------------------------------------
__device__ __forceinline__ void phase1(SmemU& sm, int bid,
    const float* __restrict__ E,  const float* __restrict__ We, const float* __restrict__ be,
    const float* __restrict__ D,  const float* __restrict__ Wt, const float* __restrict__ bt,
    const float* __restrict__ Lg, const float* __restrict__ Wl, const float* __restrict__ bl,
    float* __restrict__ uT, float* __restrict__ v1, float* __restrict__ v2,
    unsigned short* __restrict__ ET)
{
    const int tid = threadIdx.x;
    const int z = bid >> 6, t64 = bid & 63;

    if (z == 3) {
        // ---- E^T bf16 producer: two 64x64 tiles per block ----
        const int k0 = (t64 >> 2) * 64;                // p-dim tile (16)
        const int kr = tid >> 2, nc = (tid & 3) * 16;  // read coords
        const int nr = tid >> 2, kc = (tid & 3) * 16;  // write coords
        #pragma unroll
        for (int t = 0; t < 2; ++t) {
            const int n0 = ((t64 & 3) * 2 + t) * 64;   // enc-dim tile (8)
            const float* ep = E + (size_t)(k0 + kr) * ENC + n0 + nc;
            float4 a = *(const float4*)(ep + 0),  b = *(const float4*)(ep + 4);
            float4 c = *(const float4*)(ep + 8),  d = *(const float4*)(ep + 12);
            if (t) __syncthreads();
            *(uint4*)&sm.t.T[kr][nc]     = cvt8(a, b);
            *(uint4*)&sm.t.T[kr][nc + 8] = cvt8(c, d);
            __syncthreads();
            unsigned short tmp[16];
            #pragma unroll
            for (int i = 0; i < 16; ++i) tmp[i] = sm.t.T[kc + i][nr];
            unsigned short* op = ET + (size_t)(n0 + nr) * PP + k0 + kc;
            *(uint4*)(op)     = *(uint4*)&tmp[0];
            *(uint4*)(op + 8) = *(uint4*)&tmp[8];
        }
        return;
    }

    const int K = 512;
    const float *A, *B, *bias;
    if      (z == 0) { A = E;  B = We; bias = be; }
    else if (z == 1) { A = D;  B = Wt; bias = bt; }
    else             { A = Lg; B = Wl; bias = bl; }

    const int m0 = (t64 >> 2) * 64, n0 = (t64 & 3) * 64;
    const int wv = tid >> 6, lm = tid & 15, lq = (tid >> 4) & 3;
    const int mb = (wv & 1) * 32, nb = (wv >> 1) * 32;
    const int a0o = tile_off(mb + lm,      lq * 8);
    const int a1o = tile_off(mb + 16 + lm, lq * 8);
    const int b0o = tile_off(nb + lm,      lq * 8);
    const int b1o = tile_off(nb + 16 + lm, lq * 8);

    const int row = tid >> 2, kseg = tid & 3;
    const int soff = tile_off(row, kseg * 8);
    const float* Ap = A + (size_t)(m0 + row) * K + kseg * 8;
    const float* Bp = B + (size_t)(n0 + row) * K + kseg * 8;

    floatx4 acc[2][2];
    const floatx4 zero = {0.f, 0.f, 0.f, 0.f};
    acc[0][0] = zero; acc[0][1] = zero; acc[1][0] = zero; acc[1][1] = zero;

    float4 pa0 = *(const float4*)(Ap), pa1 = *(const float4*)(Ap + 4);
    float4 pb0 = *(const float4*)(Bp), pb1 = *(const float4*)(Bp + 4);

    for (int k0 = 0; k0 < K; k0 += 32) {
        const int buf = (k0 >> 5) & 1;
        *(uint4*)&sm.g.As[buf][soff] = cvt8(pa0, pa1);
        *(uint4*)&sm.g.Bs[buf][soff] = cvt8(pb0, pb1);
        __syncthreads();
        if (k0 + 32 < K) {
            pa0 = *(const float4*)(Ap + k0 + 32); pa1 = *(const float4*)(Ap + k0 + 36);
            pb0 = *(const float4*)(Bp + k0 + 32); pb1 = *(const float4*)(Bp + k0 + 36);
        }
        LdsVec fa0, fa1, fb0, fb1;
        fa0.u = *(const uint4*)&sm.g.As[buf][a0o];
        fa1.u = *(const uint4*)&sm.g.As[buf][a1o];
        fb0.u = *(const uint4*)&sm.g.Bs[buf][b0o];
        fb1.u = *(const uint4*)&sm.g.Bs[buf][b1o];
        acc[0][0] = __builtin_amdgcn_mfma_f32_16x16x32_bf16(fa0.v, fb0.v, acc[0][0], 0, 0, 0);
        acc[0][1] = __builtin_amdgcn_mfma_f32_16x16x32_bf16(fa0.v, fb1.v, acc[0][1], 0, 0, 0);
        acc[1][0] = __builtin_amdgcn_mfma_f32_16x16x32_bf16(fa1.v, fb0.v, acc[1][0], 0, 0, 0);
        acc[1][1] = __builtin_amdgcn_mfma_f32_16x16x32_bf16(fa1.v, fb1.v, acc[1][1], 0, 0, 0);
    }

    if (z == 0) {
        // transposed epilogue: uT[a][m], float4 along m
        #pragma unroll
        for (int s = 0; s < 2; ++s) {
            const int col = n0 + nb + s * 16 + lm;          // a-dim
            const float bsum = bias[col];
            #pragma unroll
            for (int t = 0; t < 2; ++t) {
                const int mbase = m0 + mb + t * 16 + lq * 4;
                float4 o;
                o.x = acc[t][s][0] + bsum; o.y = acc[t][s][1] + bsum;
                o.z = acc[t][s][2] + bsum; o.w = acc[t][s][3] + bsum;
                *(float4*)&uT[(size_t)col * NN + mbase] = o;
            }
        }
    } else {
        // normal epilogue: out[n][a]
        float* out = (z == 1) ? v1 : v2;
        #pragma unroll
        for (int s = 0; s < 2; ++s) {
            const int col = n0 + nb + s * 16 + lm;          // a-dim
            const float bsum = bias[col];
            #pragma unroll
            for (int t = 0; t < 2; ++t) {
                const int r0 = m0 + mb + t * 16 + lq * 4;   // n rows
                #pragma unroll
                for (int r = 0; r < 4; ++r)
                    out[(size_t)(r0 + r) * ATT + col] = acc[t][s][r] + bsum;
            }
        }
    }
}

// ---------------------------------------------------------------------------
// Phase 2 (256 blocks): block owns 4 n-rows x full p. Thread owns p=tid*4..+3.
//  att[n][p] = sum_a relu(uT[a][p] + v[n][a]) * Wf[a]; softmax over p fused.
//  v rows staged once in LDS (transposed [a][4], broadcast reads, no barriers
//  in main loop); u read straight from L2 (uT = 1 MB, L2-resident).
// ---------------------------------------------------------------------------
__device__ __forceinline__ void phase2(SmemU& sm, int bid,
    const float* __restrict__ uT, const float* __restrict__ v1,
    const float* __restrict__ v2, const float* __restrict__ Wf,
    float* __restrict__ alpha, unsigned short* __restrict__ alpha_bf)
{
    const int tid = threadIdx.x;
    const int n0 = bid * 4;

    {
        const size_t i0 = (size_t)(n0 + 0) * ATT + tid;
        const size_t i1 = (size_t)(n0 + 1) * ATT + tid;
        const size_t i2 = (size_t)(n0 + 2) * ATT + tid;
        const size_t i3 = (size_t)(n0 + 3) * ATT + tid;
        float4 vv;
        vv.x = v1[i0] + v2[i0];
        vv.y = v1[i1] + v2[i1];
        vv.z = v1[i2] + v2[i2];
        vv.w = v1[i3] + v2[i3];
        *(float4*)&sm.att.vsmT[tid][0] = vv;
        sm.att.wfs[tid] = Wf[tid];
    }
    __syncthreads();

    floatx2 aL[4], aH[4];
    const floatx2 z2 = {0.f, 0.f};
    #pragma unroll
    for (int r = 0; r < 4; ++r) { aL[r] = z2; aH[r] = z2; }

    const float* up = uT + tid * 4;
    #pragma unroll 8
    for (int a = 0; a < 256; ++a) {
        float4 u4 = *(const float4*)(up + (size_t)a * NN);
        float4 v4 = *(const float4*)&sm.att.vsmT[a][0];
        const float w = sm.att.wfs[a];
        floatx2 ulo = {u4.x, u4.y}, uhi = {u4.z, u4.w};
        const float vv[4] = {v4.x, v4.y, v4.z, v4.w};
        #pragma unroll
        for (int r = 0; r < 4; ++r) {
            floatx2 t0 = ulo + vv[r];
            floatx2 t1 = uhi + vv[r];
            t0 = __builtin_elementwise_max(t0, z2);
            t1 = __builtin_elementwise_max(t1, z2);
            aL[r] = t0 * w + aL[r];
            aH[r] = t1 * w + aH[r];
        }
    }

    // fused softmax across the block (rows live distributed: 4 vals/thread/row)
    const int lane = tid & 63, wv = tid >> 6;
    float m[4];
    #pragma unroll
    for (int r = 0; r < 4; ++r) {
        m[r] = fmaxf(fmaxf(aL[r][0], aL[r][1]), fmaxf(aH[r][0], aH[r][1]));
        #pragma unroll
        for (int off = 32; off > 0; off >>= 1)
            m[r] = fmaxf(m[r], __shfl_xor(m[r], off, 64));
    }
    if (lane == 0) {
        #pragma unroll
        for (int r = 0; r < 4; ++r) sm.att.red[0][wv][r] = m[r];
    }
    __syncthreads();
    float s[4];
    #pragma unroll
    for (int r = 0; r < 4; ++r) {
        m[r] = fmaxf(fmaxf(sm.att.red[0][0][r], sm.att.red[0][1][r]),
                     fmaxf(sm.att.red[0][2][r], sm.att.red[0][3][r]));
        aL[r][0] = __expf(aL[r][0] - m[r]); aL[r][1] = __expf(aL[r][1] - m[r]);
        aH[r][0] = __expf(aH[r][0] - m[r]); aH[r][1] = __expf(aH[r][1] - m[r]);
        s[r] = (aL[r][0] + aL[r][1]) + (aH[r][0] + aH[r][1]);
        #pragma unroll
        for (int off = 32; off > 0; off >>= 1) s[r] += __shfl_xor(s[r], off, 64);
    }
    if (lane == 0) {
        #pragma unroll
        for (int r = 0; r < 4; ++r) sm.att.red[1][wv][r] = s[r];
    }
    __syncthreads();
    #pragma unroll
    for (int r = 0; r < 4; ++r) {
        const float inv = 1.0f / (sm.att.red[1][0][r] + sm.att.red[1][1][r]
                                + sm.att.red[1][2][r] + sm.att.red[1][3][r]);
        float4 o;
        o.x = aL[r][0] * inv; o.y = aL[r][1] * inv;
        o.z = aH[r][0] * inv; o.w = aH[r][1] * inv;
        *(float4*)&alpha[(size_t)(n0 + r) * PP + tid * 4] = o;
        uint2 pk;
        pk.x = cvt_pk(o.x, o.y); pk.y = cvt_pk(o.z, o.w);
        *(uint2*)&alpha_bf[(size_t)(n0 + r) * PP + tid * 4] = pk;
    }
}

// ---------------------------------------------------------------------------
// Phase 4 (256 blocks): awe = alpha_bf @ ET^T, 32m x 64n tiles, BK=32.
// ---------------------------------------------------------------------------
__device__ __forceinline__ void phase4(SmemU& sm, int bid,
    const unsigned short* __restrict__ alpha_bf,
    const unsigned short* __restrict__ ET, float* __restrict__ awe)
{
    const int tid = threadIdx.x;
    const int K = PP;
    const int m0 = (bid >> 3) * 32, n0 = (bid & 7) * 64;
    const int wv = tid >> 6, lm = tid & 15, lq = (tid >> 4) & 3;
    const int mw = (wv & 1) * 16, nw = (wv >> 1) * 32;
    const int a0o = tile_off(mw + lm,      lq * 8);
    const int b0o = tile_off(nw + lm,      lq * 8);
    const int b1o = tile_off(nw + 16 + lm, lq * 8);

    const int rowA = tid >> 3, kcA = (tid & 7) * 4;
    const int rowB = tid >> 2, kcB = (tid & 3) * 8;
    const int aoff = tile_off(rowA, kcA);
    const int boff = tile_off(rowB, kcB);
    const unsigned short* Ap = alpha_bf + (size_t)(m0 + rowA) * PP + kcA;
    const unsigned short* Bp = ET + (size_t)(n0 + rowB) * PP + kcB;

    floatx4 acc[2];
    const floatx4 zero = {0.f, 0.f, 0.f, 0.f};
    acc[0] = zero; acc[1] = zero;

    uint2 pa = *(const uint2*)Ap;
    uint4 pb = *(const uint4*)Bp;

    for (int k0 = 0; k0 < K; k0 += 32) {
        const int buf = (k0 >> 5) & 1;
        *(uint2*)&sm.aw.As[buf][aoff] = pa;
        *(uint4*)&sm.aw.Bs[buf][boff] = pb;
        __syncthreads();
        if (k0 + 32 < K) {
            pa = *(const uint2*)(Ap + k0 + 32);
            pb = *(const uint4*)(Bp + k0 + 32);
        }
        LdsVec fa, fb0, fb1;
        fa.u  = *(const uint4*)&sm.aw.As[buf][a0o];
        fb0.u = *(const uint4*)&sm.aw.Bs[buf][b0o];
        fb1.u = *(const uint4*)&sm.aw.Bs[buf][b1o];
        acc[0] = __builtin_amdgcn_mfma_f32_16x16x32_bf16(fa.v, fb0.v, acc[0], 0, 0, 0);
        acc[1] = __builtin_amdgcn_mfma_f32_16x16x32_bf16(fa.v, fb1.v, acc[1], 0, 0, 0);
    }

    #pragma unroll
    for (int s = 0; s < 2; ++s) {
        const int col = n0 + nw + s * 16 + lm;
        #pragma unroll
        for (int r = 0; r < 4; ++r)
            awe[(size_t)(m0 + mw + lq * 4 + r) * ENC + col] = acc[s][r];
    }
}

// ---------------------------------------------------------------------------
// Cooperative mega-kernel: phase1 -> sync -> phase2(att+softmax) -> sync -> phase4
// ---------------------------------------------------------------------------
__global__ __launch_bounds__(256) void mega(
    const float* __restrict__ E,  const float* __restrict__ We, const float* __restrict__ be,
    const float* __restrict__ D,  const float* __restrict__ Wt, const float* __restrict__ bt,
    const float* __restrict__ Lg, const float* __restrict__ Wl, const float* __restrict__ bl,
    const float* __restrict__ Wf,
    float* __restrict__ uT, float* __restrict__ v1, float* __restrict__ v2,
    unsigned short* __restrict__ ET, unsigned short* __restrict__ alpha_bf,
    float* __restrict__ alpha, float* __restrict__ awe)
{
    __shared__ SmemU sm;
    phase1(sm, blockIdx.x, E, We, be, D, Wt, bt, Lg, Wl, bl, uT, v1, v2, ET);
    __threadfence();
    cooperative_groups::this_grid().sync();
    __threadfence();
    phase2(sm, blockIdx.x, uT, v1, v2, Wf, alpha, alpha_bf);
    __threadfence();
    cooperative_groups::this_grid().sync();
    __threadfence();
    phase4(sm, blockIdx.x, alpha_bf, ET, awe);
}

// ---- plain-launch fallbacks (same phase bodies) ----
__global__ __launch_bounds__(256) void k_p1(
    const float* __restrict__ E,  const float* __restrict__ We, const float* __restrict__ be,
    const float* __restrict__ D,  const float* __restrict__ Wt, const float* __restrict__ bt,
    const float* __restrict__ Lg, const float* __restrict__ Wl, const float* __restrict__ bl,
    float* __restrict__ uT, float* __restrict__ v1, float* __restrict__ v2,
    unsigned short* __restrict__ ET)
{
    __shared__ SmemU sm;
    phase1(sm, blockIdx.x, E, We, be, D, Wt, bt, Lg, Wl, bl, uT, v1, v2, ET);
}

__global__ __launch_bounds__(256) void k_p2(
    const float* __restrict__ uT, const float* __restrict__ v1,
    const float* __restrict__ v2, const float* __restrict__ Wf,
    float* __restrict__ alpha, unsigned short* __restrict__ alpha_bf)
{
    __shared__ SmemU sm;
    phase2(sm, blockIdx.x, uT, v1, v2, Wf, alpha, alpha_bf);
}

__global__ __launch_bounds__(256) void k_p4(
    const unsigned short* __restrict__ alpha_bf,
    const unsigned short* __restrict__ ET, float* __restrict__ awe)
{
    __shared__ SmemU sm;
    phase4(sm, blockIdx.x, alpha_bf, ET, awe);
}

// ---------------------------------------------------------------------------
extern "C" void kernel_launch(void* const* d_in, const int* in_sizes, int n_in,
                              void* d_out, int out_size, void* d_ws, size_t ws_size,
                              hipStream_t stream)
{
    const float* encoder = (const float*)d_in[0];
    const float* dec     = (const float*)d_in[1];
    const float* lang    = (const float*)d_in[2];
    const float* We      = (const float*)d_in[3];
    const float* be      = (const float*)d_in[4];
    const float* Wt      = (const float*)d_in[5];
    const float* bt      = (const float*)d_in[6];
    const float* Wl      = (const float*)d_in[7];
    const float* bl      = (const float*)d_in[8];
    const float* Wf      = (const float*)d_in[9];
    // d_in[10] = bf: uniform over p -> cancels in softmax.

    float* uT = (float*)d_ws;                    // [256][1024]
    float* v1 = uT + ATT * NN;                   // [1024][256]
    float* v2 = v1 + (size_t)NN * ATT;           // [1024][256]
    unsigned short* alpha_bf = (unsigned short*)(v2 + (size_t)NN * ATT);  // [1024][1024]
    unsigned short* ET       = alpha_bf + (size_t)NN * PP;                // [512][1024]

    float* awe   = (float*)d_out;                // (1024, 512)
    float* alpha = (float*)d_out + NN * ENC;     // (1024, 1024)

    void* args[] = {
        (void*)&encoder, (void*)&We, (void*)&be,
        (void*)&dec,     (void*)&Wt, (void*)&bt,
        (void*)&lang,    (void*)&Wl, (void*)&bl,
        (void*)&Wf,
        (void*)&uT, (void*)&v1, (void*)&v2,
        (void*)&ET, (void*)&alpha_bf, (void*)&alpha, (void*)&awe
    };

    hipError_t err = hipLaunchCooperativeKernel(
        (const void*)mega, dim3(256), dim3(256), args, 0, stream);

    if (err != hipSuccess) {
        // Fallback: same phases as 3 plain launches (graph-capture safe).
        k_p1<<<dim3(256), 256, 0, stream>>>(encoder, We, be, dec, Wt, bt,
                                            lang, Wl, bl, uT, v1, v2, ET);
        k_p2<<<dim3(256), 256, 0, stream>>>(uT, v1, v2, Wf, alpha, alpha_bf);
        k_p4<<<dim3(256), 256, 0, stream>>>(alpha_bf, ET, awe);
    }
}

// Round 2
// 123.225 us; speedup vs baseline: 2.7783x; 2.7783x over previous
//
#include <hip/hip_runtime.h>
#include <hip/hip_bf16.h>
#include <math.h>

#define ENC 512
#define ATT 256
#define NN 1024
#define PP 1024

typedef __attribute__((ext_vector_type(8))) __bf16 bf16x8;
typedef __attribute__((ext_vector_type(4))) float floatx4;
typedef __attribute__((ext_vector_type(2))) float floatx2;

union LdsVec { uint4 u; bf16x8 v; };

// packed fp32->bf16 RNE via v_cvt_pk_bf16_f32 (gfx950)
__device__ __forceinline__ unsigned cvt_pk(float lo, float hi) {
    union { __hip_bfloat162 h; unsigned u; } x;
    x.h = __float22bfloat162_rn(float2{lo, hi});
    return x.u;
}
__device__ __forceinline__ uint4 cvt8(float4 f0, float4 f1) {
    uint4 r;
    r.x = cvt_pk(f0.x, f0.y); r.y = cvt_pk(f0.z, f0.w);
    r.z = cvt_pk(f1.x, f1.y); r.w = cvt_pk(f1.z, f1.w);
    return r;
}

// LDS tile: [rows][64 k] bf16, row stride 128B; 16B granules XOR-swizzled by
// row&7 -> fragment reads (lanes 0-15 = rows, fixed k-granule) spread across
// all 32 banks, <=2-way (free per m136).
__device__ __forceinline__ int t64_off(int row, int k) {
    return row * 64 + ((((k >> 3) ^ row) & 7) << 3) + (k & 7);
}

// ---------------------------------------------------------------------------
// Kernel 1 (grid 4 x 16 x 4):
//  z=0: uT  = (E@We^T+be)^T   z=1: v1T = (D@Wt^T+bt)^T  z=2: v2T = (L@Wl^T+bl)^T
//    outputs TRANSPOSED [a=256][m=1024] so att_fused can stage without scatter.
//  z=3: ET = bf16 transpose of encoder (E^T [512][1024]) for mfma_awe.
// GEMM: 64x64 tile, BK=64 (8 barrier-iters), 16x16x32 bf16 MFMA, dbuf LDS.
// ---------------------------------------------------------------------------
__global__ __launch_bounds__(256) void mfma_uv(
    const float* __restrict__ E,  const float* __restrict__ We, const float* __restrict__ be,
    const float* __restrict__ D,  const float* __restrict__ Wt, const float* __restrict__ bt,
    const float* __restrict__ Lg, const float* __restrict__ Wl, const float* __restrict__ bl,
    float* __restrict__ uT, float* __restrict__ v1T, float* __restrict__ v2T,
    unsigned short* __restrict__ ET)
{
    const int tid = threadIdx.x;

    if (blockIdx.z == 3) {
        // ---- E^T bf16 producer: two 64x64 tiles per block ----
        __shared__ unsigned short T[64][72];           // [k][n], stride 72 u16
        const int k0 = blockIdx.y * 64;
        const int kr = tid >> 2, nc = (tid & 3) * 16;  // read coords
        const int nr = tid >> 2, kc = (tid & 3) * 16;  // write coords
        #pragma unroll
        for (int t = 0; t < 2; ++t) {
            const int n0 = (blockIdx.x * 2 + t) * 64;
            const float* ep = E + (size_t)(k0 + kr) * ENC + n0 + nc;
            float4 a = *(const float4*)(ep + 0),  b = *(const float4*)(ep + 4);
            float4 c = *(const float4*)(ep + 8),  d = *(const float4*)(ep + 12);
            if (t) __syncthreads();                    // prior reads done
            *(uint4*)&T[kr][nc]     = cvt8(a, b);
            *(uint4*)&T[kr][nc + 8] = cvt8(c, d);
            __syncthreads();
            unsigned short tmp[16];
            #pragma unroll
            for (int i = 0; i < 16; ++i) tmp[i] = T[kc + i][nr];
            unsigned short* op = ET + (size_t)(n0 + nr) * PP + k0 + kc;
            *(uint4*)(op)     = *(uint4*)&tmp[0];
            *(uint4*)(op + 8) = *(uint4*)&tmp[8];
        }
        return;
    }

    __shared__ __align__(16) unsigned short As[2][64 * 64];
    __shared__ __align__(16) unsigned short Bs[2][64 * 64];
    const int K = 512;

    const float *A, *B, *bias; float* out;
    if      (blockIdx.z == 0) { A = E;  B = We; bias = be; out = uT;  }
    else if (blockIdx.z == 1) { A = D;  B = Wt; bias = bt; out = v1T; }
    else                      { A = Lg; B = Wl; bias = bl; out = v2T; }

    const int m0 = blockIdx.y * 64, n0 = blockIdx.x * 64;
    const int wv = tid >> 6, lm = tid & 15, lq = (tid >> 4) & 3;
    const int mb = (wv & 1) * 32, nb = (wv >> 1) * 32;
    // fragment offsets: 2 m-frags x {klo,khi}, 2 n-frags x {klo,khi}
    const int a0l = t64_off(mb + lm,      lq * 8),      a0h = t64_off(mb + lm,      lq * 8 + 32);
    const int a1l = t64_off(mb + 16 + lm, lq * 8),      a1h = t64_off(mb + 16 + lm, lq * 8 + 32);
    const int b0l = t64_off(nb + lm,      lq * 8),      b0h = t64_off(nb + lm,      lq * 8 + 32);
    const int b1l = t64_off(nb + 16 + lm, lq * 8),      b1h = t64_off(nb + 16 + lm, lq * 8 + 32);

    const int row = tid >> 2, kseg = tid & 3;          // stage 2 granules/thread
    const int s0 = t64_off(row, kseg * 8);
    const int s1 = t64_off(row, kseg * 8 + 32);
    const float* Ap = A + (size_t)(m0 + row) * K + kseg * 8;
    const float* Bp = B + (size_t)(n0 + row) * K + kseg * 8;

    floatx4 acc[2][2];
    const floatx4 zero = {0.f, 0.f, 0.f, 0.f};
    acc[0][0] = zero; acc[0][1] = zero; acc[1][0] = zero; acc[1][1] = zero;

    float4 pa0 = *(const float4*)(Ap),      pa1 = *(const float4*)(Ap + 4);
    float4 pa2 = *(const float4*)(Ap + 32), pa3 = *(const float4*)(Ap + 36);
    float4 pb0 = *(const float4*)(Bp),      pb1 = *(const float4*)(Bp + 4);
    float4 pb2 = *(const float4*)(Bp + 32), pb3 = *(const float4*)(Bp + 36);

    for (int k0 = 0; k0 < K; k0 += 64) {
        const int buf = (k0 >> 6) & 1;
        *(uint4*)&As[buf][s0] = cvt8(pa0, pa1);
        *(uint4*)&As[buf][s1] = cvt8(pa2, pa3);
        *(uint4*)&Bs[buf][s0] = cvt8(pb0, pb1);
        *(uint4*)&Bs[buf][s1] = cvt8(pb2, pb3);
        __syncthreads();
        if (k0 + 64 < K) {
            pa0 = *(const float4*)(Ap + k0 + 64); pa1 = *(const float4*)(Ap + k0 + 68);
            pa2 = *(const float4*)(Ap + k0 + 96); pa3 = *(const float4*)(Ap + k0 + 100);
            pb0 = *(const float4*)(Bp + k0 + 64); pb1 = *(const float4*)(Bp + k0 + 68);
            pb2 = *(const float4*)(Bp + k0 + 96); pb3 = *(const float4*)(Bp + k0 + 100);
        }
        LdsVec fa0l, fa0h, fa1l, fa1h, fb0l, fb0h, fb1l, fb1h;
        fa0l.u = *(const uint4*)&As[buf][a0l];  fa0h.u = *(const uint4*)&As[buf][a0h];
        fa1l.u = *(const uint4*)&As[buf][a1l];  fa1h.u = *(const uint4*)&As[buf][a1h];
        fb0l.u = *(const uint4*)&Bs[buf][b0l];  fb0h.u = *(const uint4*)&Bs[buf][b0h];
        fb1l.u = *(const uint4*)&Bs[buf][b1l];  fb1h.u = *(const uint4*)&Bs[buf][b1h];
        acc[0][0] = __builtin_amdgcn_mfma_f32_16x16x32_bf16(fa0l.v, fb0l.v, acc[0][0], 0, 0, 0);
        acc[0][1] = __builtin_amdgcn_mfma_f32_16x16x32_bf16(fa0l.v, fb1l.v, acc[0][1], 0, 0, 0);
        acc[1][0] = __builtin_amdgcn_mfma_f32_16x16x32_bf16(fa1l.v, fb0l.v, acc[1][0], 0, 0, 0);
        acc[1][1] = __builtin_amdgcn_mfma_f32_16x16x32_bf16(fa1l.v, fb1l.v, acc[1][1], 0, 0, 0);
        acc[0][0] = __builtin_amdgcn_mfma_f32_16x16x32_bf16(fa0h.v, fb0h.v, acc[0][0], 0, 0, 0);
        acc[0][1] = __builtin_amdgcn_mfma_f32_16x16x32_bf16(fa0h.v, fb1h.v, acc[0][1], 0, 0, 0);
        acc[1][0] = __builtin_amdgcn_mfma_f32_16x16x32_bf16(fa1h.v, fb0h.v, acc[1][0], 0, 0, 0);
        acc[1][1] = __builtin_amdgcn_mfma_f32_16x16x32_bf16(fa1h.v, fb1h.v, acc[1][1], 0, 0, 0);
    }

    // transposed epilogue: out[a][m], float4 along m (r index)
    #pragma unroll
    for (int s = 0; s < 2; ++s) {
        const int col = n0 + nb + s * 16 + lm;          // a-dim
        const float bsum = bias[col];
        #pragma unroll
        for (int t = 0; t < 2; ++t) {
            const int mbase = m0 + mb + t * 16 + lq * 4;
            float4 o;
            o.x = acc[t][s][0] + bsum; o.y = acc[t][s][1] + bsum;
            o.z = acc[t][s][2] + bsum; o.w = acc[t][s][3] + bsum;
            *(float4*)&out[(size_t)col * NN + mbase] = o;
        }
    }
}

// ---------------------------------------------------------------------------
// Kernel 2: att[n,p] = sum_a relu(uT[a,p] + v1T[a,n] + v2T[a,n]) * Wf[a]
// Tile 64p x 64n, thread 4p x 4n. z splits a-range in half -> 512 blocks
// (2 blocks/CU); partials summed in softmax.
// ---------------------------------------------------------------------------
__global__ __launch_bounds__(256) void att_fused(
    const float* __restrict__ uT, const float* __restrict__ v1T,
    const float* __restrict__ v2T,
    const float* __restrict__ Wf, float* __restrict__ att_part)
{
    __shared__ float us[32][68];
    __shared__ float vs[32][68];
    __shared__ float wfs[128];
    const int tid = threadIdx.x;
    const int z = blockIdx.z;
    if (tid < 128) wfs[tid] = Wf[z * 128 + tid];
    const int p0 = blockIdx.x * 64, n0 = blockIdx.y * 64;
    const int rowS = tid >> 3, cS = (tid & 7) * 8;   // staging coords
    const int tx = tid & 15, ty = tid >> 4;          // p = tx*4, n = ty*4

    floatx2 acc[4][2];
    const floatx2 z2 = {0.f, 0.f};
    #pragma unroll
    for (int j = 0; j < 4; ++j) { acc[j][0] = z2; acc[j][1] = z2; }

    const int abase = z * 128;
    for (int ac = 0; ac < 128; ac += 32) {
        __syncthreads();
        {
            const float* up = &uT[(size_t)(abase + ac + rowS) * NN + p0 + cS];
            float4 f0 = *(const float4*)up;
            float4 f1 = *(const float4*)(up + 4);
            *(float4*)&us[rowS][cS]     = f0;
            *(float4*)&us[rowS][cS + 4] = f1;
            const size_t vidx = (size_t)(abase + ac + rowS) * NN + n0 + cS;
            float4 g0 = *(const float4*)&v1T[vidx];
            float4 g1 = *(const float4*)&v1T[vidx + 4];
            float4 h0 = *(const float4*)&v2T[vidx];
            float4 h1 = *(const float4*)&v2T[vidx + 4];
            float4 s0, s1;
            s0.x = g0.x + h0.x; s0.y = g0.y + h0.y; s0.z = g0.z + h0.z; s0.w = g0.w + h0.w;
            s1.x = g1.x + h1.x; s1.y = g1.y + h1.y; s1.z = g1.z + h1.z; s1.w = g1.w + h1.w;
            *(float4*)&vs[rowS][cS]     = s0;
            *(float4*)&vs[rowS][cS + 4] = s1;
        }
        __syncthreads();
        #pragma unroll
        for (int a4 = 0; a4 < 32; a4 += 4) {
            float4 w4 = *(const float4*)&wfs[ac + a4];
            #pragma unroll
            for (int aa = 0; aa < 4; ++aa) {
                const int a = a4 + aa;
                float4 u4 = *(const float4*)&us[a][tx * 4];
                float4 v4 = *(const float4*)&vs[a][ty * 4];
                const float w = (aa == 0) ? w4.x : (aa == 1) ? w4.y : (aa == 2) ? w4.z : w4.w;
                floatx2 ulo = {u4.x, u4.y}, uhi = {u4.z, u4.w};
                const float vv[4] = {v4.x, v4.y, v4.z, v4.w};
                #pragma unroll
                for (int j = 0; j < 4; ++j) {
                    floatx2 t0 = ulo + vv[j];
                    floatx2 t1 = uhi + vv[j];
                    t0 = __builtin_elementwise_max(t0, z2);
                    t1 = __builtin_elementwise_max(t1, z2);
                    acc[j][0] = t0 * w + acc[j][0];
                    acc[j][1] = t1 * w + acc[j][1];
                }
            }
        }
    }

    float* outp = att_part + (size_t)z * NN * PP;
    #pragma unroll
    for (int j = 0; j < 4; ++j) {
        float4 o;
        o.x = acc[j][0].x; o.y = acc[j][0].y; o.z = acc[j][1].x; o.w = acc[j][1].y;
        *(float4*)&outp[(size_t)(n0 + ty * 4 + j) * PP + p0 + tx * 4] = o;
    }
}

// ---------------------------------------------------------------------------
// Kernel 3: softmax over p of (att_part0 + att_part1); writes fp32 alpha to
// d_out AND bf16 alpha to ws for mfma_awe.  Wave-per-row, no barriers.
// ---------------------------------------------------------------------------
__global__ __launch_bounds__(256) void softmax_rows(
    const float* __restrict__ att_part, float* __restrict__ alpha,
    unsigned short* __restrict__ alpha_bf)
{
    const int wv = threadIdx.x >> 6, lane = threadIdx.x & 63;
    const int n = blockIdx.x * 4 + wv;
    const float* r0 = att_part + (size_t)n * PP;
    const float* r1 = att_part + (size_t)NN * PP + (size_t)n * PP;

    float4 x[4];
    #pragma unroll
    for (int i = 0; i < 4; ++i) {
        float4 a = *(const float4*)&r0[i * 256 + lane * 4];
        float4 b = *(const float4*)&r1[i * 256 + lane * 4];
        x[i].x = a.x + b.x; x[i].y = a.y + b.y; x[i].z = a.z + b.z; x[i].w = a.w + b.w;
    }

    float m = -1e30f;
    #pragma unroll
    for (int i = 0; i < 4; ++i)
        m = fmaxf(m, fmaxf(fmaxf(x[i].x, x[i].y), fmaxf(x[i].z, x[i].w)));
    #pragma unroll
    for (int off = 32; off > 0; off >>= 1) m = fmaxf(m, __shfl_xor(m, off, 64));

    float s = 0.f;
    #pragma unroll
    for (int i = 0; i < 4; ++i) {
        x[i].x = __expf(x[i].x - m); x[i].y = __expf(x[i].y - m);
        x[i].z = __expf(x[i].z - m); x[i].w = __expf(x[i].w - m);
        s += x[i].x + x[i].y + x[i].z + x[i].w;
    }
    #pragma unroll
    for (int off = 32; off > 0; off >>= 1) s += __shfl_xor(s, off, 64);
    const float inv = 1.0f / s;

    float* ar = alpha + (size_t)n * PP;
    unsigned short* br = alpha_bf + (size_t)n * PP;
    #pragma unroll
    for (int i = 0; i < 4; ++i) {
        x[i].x *= inv; x[i].y *= inv; x[i].z *= inv; x[i].w *= inv;
        *(float4*)&ar[i * 256 + lane * 4] = x[i];
        uint2 pk;
        pk.x = cvt_pk(x[i].x, x[i].y);
        pk.y = cvt_pk(x[i].z, x[i].w);
        *(uint2*)&br[i * 256 + lane * 4] = pk;
    }
}

// ---------------------------------------------------------------------------
// Kernel 4: awe = alpha @ E, both operands pre-converted bf16 (alpha_bf, ET).
// Tile 32m x 64n, BK=64 (16 barrier-iters), 256 blocks, pure copy staging.
// ---------------------------------------------------------------------------
__global__ __launch_bounds__(256) void mfma_awe(
    const unsigned short* __restrict__ alpha_bf,
    const unsigned short* __restrict__ ET, float* __restrict__ awe)
{
    __shared__ __align__(16) unsigned short As[2][32 * 64];
    __shared__ __align__(16) unsigned short Bs[2][64 * 64];
    const int tid = threadIdx.x;
    const int K = PP;
    const int m0 = blockIdx.y * 32, n0 = blockIdx.x * 64;
    const int wv = tid >> 6, lm = tid & 15, lq = (tid >> 4) & 3;
    const int mw = (wv & 1) * 16, nw = (wv >> 1) * 32;
    const int aol = t64_off(mw + lm,      lq * 8),  aoh = t64_off(mw + lm,      lq * 8 + 32);
    const int b0l = t64_off(nw + lm,      lq * 8),  b0h = t64_off(nw + lm,      lq * 8 + 32);
    const int b1l = t64_off(nw + 16 + lm, lq * 8),  b1h = t64_off(nw + 16 + lm, lq * 8 + 32);

    const int rowA = tid >> 3, kcA = (tid & 7) * 8;   // one uint4 per thread (full 32x64)
    const int rowB = tid >> 2, kcB = (tid & 3) * 8;   // two uint4 per thread
    const int aoff  = t64_off(rowA, kcA);
    const int boff0 = t64_off(rowB, kcB);
    const int boff1 = t64_off(rowB, kcB + 32);
    const unsigned short* Ap = alpha_bf + (size_t)(m0 + rowA) * PP + kcA;
    const unsigned short* Bp = ET + (size_t)(n0 + rowB) * PP + kcB;

    floatx4 acc[2];
    const floatx4 zero = {0.f, 0.f, 0.f, 0.f};
    acc[0] = zero; acc[1] = zero;

    uint4 pa  = *(const uint4*)Ap;
    uint4 pb0 = *(const uint4*)Bp;
    uint4 pb1 = *(const uint4*)(Bp + 32);

    for (int k0 = 0; k0 < K; k0 += 64) {
        const int buf = (k0 >> 6) & 1;
        *(uint4*)&As[buf][aoff]  = pa;
        *(uint4*)&Bs[buf][boff0] = pb0;
        *(uint4*)&Bs[buf][boff1] = pb1;
        __syncthreads();
        if (k0 + 64 < K) {
            pa  = *(const uint4*)(Ap + k0 + 64);
            pb0 = *(const uint4*)(Bp + k0 + 64);
            pb1 = *(const uint4*)(Bp + k0 + 96);
        }
        LdsVec fal, fah, fb0l, fb0h, fb1l, fb1h;
        fal.u  = *(const uint4*)&As[buf][aol];
        fah.u  = *(const uint4*)&As[buf][aoh];
        fb0l.u = *(const uint4*)&Bs[buf][b0l];
        fb0h.u = *(const uint4*)&Bs[buf][b0h];
        fb1l.u = *(const uint4*)&Bs[buf][b1l];
        fb1h.u = *(const uint4*)&Bs[buf][b1h];
        acc[0] = __builtin_amdgcn_mfma_f32_16x16x32_bf16(fal.v, fb0l.v, acc[0], 0, 0, 0);
        acc[1] = __builtin_amdgcn_mfma_f32_16x16x32_bf16(fal.v, fb1l.v, acc[1], 0, 0, 0);
        acc[0] = __builtin_amdgcn_mfma_f32_16x16x32_bf16(fah.v, fb0h.v, acc[0], 0, 0, 0);
        acc[1] = __builtin_amdgcn_mfma_f32_16x16x32_bf16(fah.v, fb1h.v, acc[1], 0, 0, 0);
    }

    #pragma unroll
    for (int s = 0; s < 2; ++s) {
        const int col = n0 + nw + s * 16 + lm;
        #pragma unroll
        for (int r = 0; r < 4; ++r)
            awe[(size_t)(m0 + mw + lq * 4 + r) * ENC + col] = acc[s][r];
    }
}

// ---------------------------------------------------------------------------
extern "C" void kernel_launch(void* const* d_in, const int* in_sizes, int n_in,
                              void* d_out, int out_size, void* d_ws, size_t ws_size,
                              hipStream_t stream)
{
    const float* encoder = (const float*)d_in[0];
    const float* dec     = (const float*)d_in[1];
    const float* lang    = (const float*)d_in[2];
    const float* We      = (const float*)d_in[3];
    const float* be      = (const float*)d_in[4];
    const float* Wt      = (const float*)d_in[5];
    const float* bt      = (const float*)d_in[6];
    const float* Wl      = (const float*)d_in[7];
    const float* bl      = (const float*)d_in[8];
    const float* Wf      = (const float*)d_in[9];
    // d_in[10] = bf: uniform over p -> cancels in softmax.

    float* uT   = (float*)d_ws;                  // [256][1024]
    float* v1T  = uT  + ATT * NN;                // [256][1024]
    float* v2T  = v1T + ATT * NN;                // [256][1024]
    float* attp = v2T + ATT * NN;                // [2][1024][1024]
    unsigned short* alpha_bf = (unsigned short*)(attp + 2 * (size_t)NN * PP);  // [1024][1024]
    unsigned short* ET       = alpha_bf + (size_t)NN * PP;                     // [512][1024]

    float* awe   = (float*)d_out;                // (1024, 512)
    float* alpha = (float*)d_out + NN * ENC;     // (1024, 1024)

    mfma_uv<<<dim3(4, 16, 4), 256, 0, stream>>>(
        encoder, We, be, dec, Wt, bt, lang, Wl, bl, uT, v1T, v2T, ET);
    att_fused<<<dim3(PP / 64, NN / 64, 2), 256, 0, stream>>>(uT, v1T, v2T, Wf, attp);
    softmax_rows<<<dim3(NN / 4), 256, 0, stream>>>(attp, alpha, alpha_bf);
    mfma_awe<<<dim3(ENC / 64, NN / 32), 256, 0, stream>>>(alpha_bf, ET, awe);
}